// Round 1
// 379.172 us; speedup vs baseline: 1.0820x; 1.0820x over previous
//
#include <hip/hip_runtime.h>
#include <hip/hip_bf16.h>

#define NN 16384   // N_NODES
#define KK 50      // K neighbors
#define DD 64      // EMBED_DIM

typedef __attribute__((ext_vector_type(8))) short bf16x8;   // 8 bf16 (4 VGPRs)
typedef __attribute__((ext_vector_type(4))) float f32x4;    // MFMA C/D

// ---------- bf16 helpers ----------
__device__ __forceinline__ float bf2f(unsigned short u) {
    union { unsigned int i; float f; } v;
    v.i = ((unsigned int)u) << 16;
    return v.f;
}
__device__ __forceinline__ unsigned short f2bf(float f) {
    union { float f; unsigned int i; } v; v.f = f;
    unsigned int lsb = (v.i >> 16) & 1u;
    v.i += 0x7fffu + lsb;                 // RTNE
    return (unsigned short)(v.i >> 16);
}
// pack two f32 -> one u32 of 2x bf16 (RTNE), src0 -> low half
__device__ __forceinline__ unsigned int pk2bf(float lo, float hi) {
    unsigned int w;
    asm("v_cvt_pk_bf16_f32 %0, %1, %2" : "=v"(w) : "v"(lo), "v"(hi));
    return w;
}

template<int BF16>
__device__ __forceinline__ float ldv(const void* p, size_t i) {
    if (BF16) return bf2f(((const unsigned short*)p)[i]);
    else      return ((const float*)p)[i];
}

template<int BF16>
__device__ __forceinline__ f32x4 ld4(const void* p, size_t i) {
    if (BF16) {
        const ushort4 u = *(const ushort4*)((const unsigned short*)p + i);
        return (f32x4){bf2f(u.x), bf2f(u.y), bf2f(u.z), bf2f(u.w)};
    } else {
        return *(const f32x4*)((const float*)p + i);
    }
}

// 8 contiguous elements -> bf16x8 fragment.
// f32 path: two dwordx4 loads + 4 cvt_pk (was: 8 scalar loads + ~32 VALU).
template<int BF16>
__device__ __forceinline__ bf16x8 load8(const void* p, size_t off) {
    if (BF16) {
        return *(const bf16x8*)((const unsigned short*)p + off);   // 16B
    } else {
        const float* f = (const float*)p + off;                    // 32B aligned
        const f32x4 a = *(const f32x4*)f;
        const f32x4 b = *(const f32x4*)(f + 4);
        union { bf16x8 v; unsigned int w[4]; } r;
        r.w[0] = pk2bf(a[0], a[1]);
        r.w[1] = pk2bf(a[2], a[3]);
        r.w[2] = pk2bf(b[0], b[1]);
        r.w[3] = pk2bf(b[2], b[3]);
        return r.v;
    }
}

// ---------- probe + weight repack (one block, 1024 threads) ----------
// flags[0]: neigh_mask uint8(1)/int32(0); flags[1]: tensors bf16(1)/f32(0)
// Packed as B-fragments of W (== A-fragments of W^T, bit-identical):
//   frag fl = kt*4 + ct, lane l holds W[k = kt*32 + (l>>4)*8 + j][c = ct*16 + (l&15)]
__global__ void prep_kernel(const unsigned int* __restrict__ tw,
                            const unsigned int* __restrict__ mw,
                            const void* __restrict__ W1_,
                            const void* __restrict__ W2_,
                            int* __restrict__ flags,
                            unsigned short* __restrict__ W1top,
                            unsigned short* __restrict__ W1bot,
                            unsigned short* __restrict__ W2p) {
    __shared__ int sflags[2];
    const int t = threadIdx.x;            // 1024
    if (t < 64) {
        const unsigned int w  = tw[t];
        const unsigned int lo = w & 0xFFFFu;
        const unsigned int ex = (lo >> 7) & 0xFFu;
        const bool bf_like = (ex >= 96u && ex <= 126u);
        const unsigned long long bb = __ballot(bf_like);
        bool found = false;
#pragma unroll
        for (int i = 0; i < 8; ++i) found |= (mw[t + i * 64] > 1u);
        const unsigned long long mb = __ballot(found);
        if (t == 0) {
            sflags[0] = (mb != 0ull) ? 1 : 0;
            sflags[1] = (__popcll(bb) >= 48) ? 1 : 0;
            flags[0] = sflags[0];
            flags[1] = sflags[1];
        }
    }
    __syncthreads();
    const int bf = sflags[1];
    {   // W1 [128x64]: 16 fragments; kt<2 -> top (E half), kt>=2 -> bot (U half)
        const int f = t >> 6, lane = t & 63;
        const int kt = f >> 2, nt = f & 3;
        const int q = lane >> 4, col = lane & 15;
#pragma unroll
        for (int j = 0; j < 8; ++j) {
            const int k = kt * 32 + q * 8 + j;
            const int n = nt * 16 + col;
            const float v = bf ? bf2f(((const unsigned short*)W1_)[k * 64 + n])
                               : ((const float*)W1_)[k * 64 + n];
            unsigned short* dst = (kt < 2) ? W1top : W1bot;
            const int fl = ((kt & 1) * 4 + nt);
            dst[((size_t)fl * 64 + lane) * 8 + j] = f2bf(v);
        }
    }
    if (t < 512) {   // W2 [64x64]: 8 fragments
        const int f = t >> 6, lane = t & 63;
        const int kt = f >> 2, nt = f & 3;
        const int q = lane >> 4, col = lane & 15;
#pragma unroll
        for (int j = 0; j < 8; ++j) {
            const int k = kt * 32 + q * 8 + j;
            const int n = nt * 16 + col;
            const float v = bf ? bf2f(((const unsigned short*)W2_)[k * 64 + n])
                               : ((const float*)W2_)[k * 64 + n];
            W2p[((size_t)f * 64 + lane) * 8 + j] = f2bf(v);
        }
    }
}

// ---------- UW precompute: UW[n][c] = b1[c] + table[nodes[n]] @ W1_bot ----------
// 64 nodes per wave, 4 waves/block, 64 blocks. Output f32 [NN x 64].
template<int BF16>
__device__ __forceinline__ void uw_impl(
    const void* __restrict__ table_, const void* __restrict__ b1_,
    const int* __restrict__ nodes,
    const unsigned short* __restrict__ W1bot,
    float* __restrict__ UW)
{
    const int wave = threadIdx.x >> 6;
    const int lane = threadIdx.x & 63;
    const int q    = lane >> 4;
    const int col  = lane & 15;
    const int base = (blockIdx.x * 4 + wave) * 64;

    bf16x8 afrag[4][2];
#pragma unroll
    for (int mt = 0; mt < 4; ++mt) {
        const size_t row = (size_t)nodes[base + mt * 16 + col];
#pragma unroll
        for (int kt = 0; kt < 2; ++kt)
            afrag[mt][kt] = load8<BF16>(table_, row * 64 + kt * 32 + q * 8);
    }

    f32x4 acc[4][4];
#pragma unroll
    for (int mt = 0; mt < 4; ++mt)
#pragma unroll
        for (int nt = 0; nt < 4; ++nt) acc[mt][nt] = (f32x4){0.f, 0.f, 0.f, 0.f};

#pragma unroll
    for (int kt = 0; kt < 2; ++kt)
#pragma unroll
        for (int nt = 0; nt < 4; ++nt) {
            const bf16x8 b = *(const bf16x8*)(W1bot + ((size_t)(kt * 4 + nt) * 64 + lane) * 8);
#pragma unroll
            for (int mt = 0; mt < 4; ++mt)
                acc[mt][nt] = __builtin_amdgcn_mfma_f32_16x16x32_bf16(afrag[mt][kt], b, acc[mt][nt], 0, 0, 0);
        }

    float b1v[4];
#pragma unroll
    for (int nt = 0; nt < 4; ++nt) b1v[nt] = ldv<BF16>(b1_, nt * 16 + col);
#pragma unroll
    for (int mt = 0; mt < 4; ++mt)
#pragma unroll
        for (int nt = 0; nt < 4; ++nt)
#pragma unroll
            for (int r = 0; r < 4; ++r)
                UW[(size_t)(base + mt * 16 + q * 4 + r) * 64 + nt * 16 + col] =
                    acc[mt][nt][r] + b1v[nt];
}

__global__ __launch_bounds__(256) void uw_kernel(
    const void* __restrict__ table_, const void* __restrict__ b1_,
    const int* __restrict__ nodes, const int* __restrict__ flags,
    const unsigned short* __restrict__ W1bot, float* __restrict__ UW)
{
    if (flags[1]) uw_impl<1>(table_, b1_, nodes, W1bot, UW);
    else          uw_impl<0>(table_, b1_, nodes, W1bot, UW);
}

// ---------- main: one wave per node, 2 waves/block ----------
// TRANSPOSED scheme: A-frag(M) == B-frag(M^T) bit-for-bit, so
//   mfma(Wfrag, Efrag) computes H^T[c][m] directly. Lane then owns
//   h[m = mt*16+col][c = ct*16+q*4+r] -> packs to LDS as b64 pairs,
//   scores/softmax/att are lane-local over the same m = mt*16+col the
//   E-fragments live on (no ballot, no att broadcast).
template<int BF16>
__device__ __forceinline__ void agg_impl(
    const void* __restrict__ table_,
    const void* __restrict__ b2_, const void* __restrict__ W3_,
    const int*  __restrict__ neigh_idx,
    const void* __restrict__ neigh_mask,
    int mu8,
    const unsigned short* __restrict__ W1top,
    const unsigned short* __restrict__ W2p,
    const float* __restrict__ UW,
    unsigned short* __restrict__ h1,     // per-wave [64][72] bf16 (h[m][c])
    float* __restrict__ scr,             // per-wave [64] f32
    void* __restrict__ out_)
{
    const int lane = threadIdx.x & 63;
    const int n    = blockIdx.x * 2 + (threadIdx.x >> 6);
    const int q    = lane >> 4;
    const int col  = lane & 15;

    // --- indices + mask: issue both loads in parallel (no mask->idx chain);
    //     masked/padded rows redirected to row 0 (keeps gather traffic halved) ---
    int  rowidx [4];
    bool rowmask[4];
#pragma unroll
    for (int mt = 0; mt < 4; ++mt) {
        const int k  = mt * 16 + col;
        const int kc = (k < KK) ? k : (KK - 1);
        const int ir = neigh_idx[(size_t)n * KK + kc];
        bool mk = mu8 ? (((const unsigned char*)neigh_mask)[(size_t)n * KK + kc] != 0)
                      : (((const int*)neigh_mask)[(size_t)n * KK + kc] != 0);
        mk = mk && (k < KK);
        rowmask[mt] = mk;
        rowidx[mt]  = mk ? ir : 0;
    }

    // --- gather E rows (kept live for the final weighted sum) ---
    bf16x8 afrag[4][2];
#pragma unroll
    for (int mt = 0; mt < 4; ++mt)
#pragma unroll
        for (int kt = 0; kt < 2; ++kt)
            afrag[mt][kt] = load8<BF16>(table_, (size_t)rowidx[mt] * 64 + kt * 32 + q * 8);

    // --- layer 1 transposed, streamed over c-tiles:
    //     acc[mt][r] = H[m=mt*16+col][c=ct*16+q*4+r] ---
#pragma unroll
    for (int ct = 0; ct < 4; ++ct) {
        const bf16x8 wA0 = *(const bf16x8*)(W1top + ((size_t)(0 * 4 + ct) * 64 + lane) * 8);
        const bf16x8 wA1 = *(const bf16x8*)(W1top + ((size_t)(1 * 4 + ct) * 64 + lane) * 8);
        f32x4 acc[4];
#pragma unroll
        for (int mt = 0; mt < 4; ++mt) acc[mt] = (f32x4){0.f, 0.f, 0.f, 0.f};
#pragma unroll
        for (int mt = 0; mt < 4; ++mt)
            acc[mt] = __builtin_amdgcn_mfma_f32_16x16x32_bf16(wA0, afrag[mt][0], acc[mt], 0, 0, 0);
#pragma unroll
        for (int mt = 0; mt < 4; ++mt)
            acc[mt] = __builtin_amdgcn_mfma_f32_16x16x32_bf16(wA1, afrag[mt][1], acc[mt], 0, 0, 0);

        const f32x4 uw4 = *(const f32x4*)&UW[(size_t)n * 64 + ct * 16 + q * 4];
#pragma unroll
        for (int mt = 0; mt < 4; ++mt) {
            const float h0 = fmaxf(acc[mt][0] + uw4[0], 0.f);
            const float hv1 = fmaxf(acc[mt][1] + uw4[1], 0.f);
            const float h2 = fmaxf(acc[mt][2] + uw4[2], 0.f);
            const float h3 = fmaxf(acc[mt][3] + uw4[3], 0.f);
            uint2 w;                       // 4 consecutive c -> one b64 store
            w.x = pk2bf(h0, hv1);
            w.y = pk2bf(h2, h3);
            *(uint2*)&h1[(size_t)(mt * 16 + col) * 72 + ct * 16 + q * 4] = w;
        }
    }
    __builtin_amdgcn_wave_barrier();

    // --- B2 fragments: lane reads h[m=mt*16+col][c = kt2*32+q*8+j] (b128) ---
    bf16x8 bfrag[4][2];
#pragma unroll
    for (int mt = 0; mt < 4; ++mt)
#pragma unroll
        for (int kt = 0; kt < 2; ++kt)
            bfrag[mt][kt] = *(const bf16x8*)&h1[(size_t)(mt * 16 + col) * 72 + kt * 32 + q * 8];

    // --- layer 2 transposed, streamed over c'-tiles; fold b2/W3 immediately ---
    float p[4] = {0.f, 0.f, 0.f, 0.f};
#pragma unroll
    for (int ct = 0; ct < 4; ++ct) {
        const bf16x8 wB0 = *(const bf16x8*)(W2p + ((size_t)(0 * 4 + ct) * 64 + lane) * 8);
        const bf16x8 wB1 = *(const bf16x8*)(W2p + ((size_t)(1 * 4 + ct) * 64 + lane) * 8);
        f32x4 acc[4];
#pragma unroll
        for (int mt = 0; mt < 4; ++mt) acc[mt] = (f32x4){0.f, 0.f, 0.f, 0.f};
#pragma unroll
        for (int mt = 0; mt < 4; ++mt)
            acc[mt] = __builtin_amdgcn_mfma_f32_16x16x32_bf16(wB0, bfrag[mt][0], acc[mt], 0, 0, 0);
#pragma unroll
        for (int mt = 0; mt < 4; ++mt)
            acc[mt] = __builtin_amdgcn_mfma_f32_16x16x32_bf16(wB1, bfrag[mt][1], acc[mt], 0, 0, 0);

        const f32x4 b2v = ld4<BF16>(b2_, ct * 16 + q * 4);
        const f32x4 w3v = ld4<BF16>(W3_, ct * 16 + q * 4);
#pragma unroll
        for (int mt = 0; mt < 4; ++mt) {
            float t = 0.f;
#pragma unroll
            for (int r = 0; r < 4; ++r)
                t += fmaxf(acc[mt][r] + b2v[r], 0.f) * w3v[r];
            p[mt] += t;
        }
    }

    // --- finish scores: sum the 4 q-lanes, apply mask ---
#pragma unroll
    for (int mt = 0; mt < 4; ++mt) {
        p[mt] += __shfl_xor(p[mt], 16, 64);
        p[mt] += __shfl_xor(p[mt], 32, 64);
        if (!rowmask[mt]) p[mt] = -1.0e30f;
    }

    // --- masked softmax over 64 m (4 per lane x 16 cols, replicated over q) ---
    float mx = fmaxf(fmaxf(p[0], p[1]), fmaxf(p[2], p[3]));
    mx = fmaxf(mx, __shfl_xor(mx, 1, 64));
    mx = fmaxf(mx, __shfl_xor(mx, 2, 64));
    mx = fmaxf(mx, __shfl_xor(mx, 4, 64));
    mx = fmaxf(mx, __shfl_xor(mx, 8, 64));

    float e[4], ls = 0.f;
#pragma unroll
    for (int mt = 0; mt < 4; ++mt) { e[mt] = __expf(p[mt] - mx); ls += e[mt]; }
    ls += __shfl_xor(ls, 1, 64);
    ls += __shfl_xor(ls, 2, 64);
    ls += __shfl_xor(ls, 4, 64);
    ls += __shfl_xor(ls, 8, 64);
    const float inv = 1.f / ls;

    // att[m=mt*16+col] lands exactly on the lanes holding E[m] — no broadcast.
    float att[4];
#pragma unroll
    for (int mt = 0; mt < 4; ++mt) att[mt] = e[mt] * inv;

    // --- out[d] = sum_m att[m]*E[m][d] from the live fragments ---
    float v[2][8];
#pragma unroll
    for (int kt = 0; kt < 2; ++kt)
#pragma unroll
        for (int j = 0; j < 8; ++j) v[kt][j] = 0.f;
#pragma unroll
    for (int mt = 0; mt < 4; ++mt)
#pragma unroll
        for (int kt = 0; kt < 2; ++kt)
#pragma unroll
            for (int j = 0; j < 8; ++j)
                v[kt][j] += att[mt] * bf2f(((const unsigned short*)&afrag[mt][kt])[j]);

#pragma unroll
    for (int off = 1; off <= 8; off <<= 1)
#pragma unroll
        for (int kt = 0; kt < 2; ++kt)
#pragma unroll
            for (int j = 0; j < 8; ++j)
                v[kt][j] += __shfl_xor(v[kt][j], off, 64);

    if (col == 0) {
#pragma unroll
        for (int kt = 0; kt < 2; ++kt) {
            *(f32x4*)&scr[kt * 32 + q * 8]     = (f32x4){v[kt][0], v[kt][1], v[kt][2], v[kt][3]};
            *(f32x4*)&scr[kt * 32 + q * 8 + 4] = (f32x4){v[kt][4], v[kt][5], v[kt][6], v[kt][7]};
        }
    }
    __builtin_amdgcn_wave_barrier();

    const float res = scr[lane];
    if (BF16) ((unsigned short*)out_)[(size_t)n * 64 + lane] = f2bf(res);
    else      ((float*)out_)[(size_t)n * 64 + lane] = res;
}

__global__ __launch_bounds__(128, 4) void agg_kernel(
    const void* __restrict__ table_,
    const void* __restrict__ b2_, const void* __restrict__ W3_,
    const int*  __restrict__ neigh_idx,
    const void* __restrict__ neigh_mask,
    const int*  __restrict__ flags,
    const unsigned short* __restrict__ W1top,
    const unsigned short* __restrict__ W2p,
    const float* __restrict__ UW,
    void* __restrict__ out_)
{
    __shared__ unsigned short h1_sh[2][64][72];
    __shared__ float scr_sh[2][64];
    const int wave = threadIdx.x >> 6;
    if (flags[1])
        agg_impl<1>(table_, b2_, W3_, neigh_idx, neigh_mask, flags[0],
                    W1top, W2p, UW, &h1_sh[wave][0][0], &scr_sh[wave][0], out_);
    else
        agg_impl<0>(table_, b2_, W3_, neigh_idx, neigh_mask, flags[0],
                    W1top, W2p, UW, &h1_sh[wave][0][0], &scr_sh[wave][0], out_);
}

extern "C" void kernel_launch(void* const* d_in, const int* in_sizes, int n_in,
                              void* d_out, int out_size, void* d_ws, size_t ws_size,
                              hipStream_t stream) {
    const void* table = d_in[0];
    const void* W1    = d_in[1];
    const void* b1    = d_in[2];
    const void* W2    = d_in[3];
    const void* b2    = d_in[4];
    const void* W3    = d_in[5];
    const void* b3    = d_in[6]; (void)b3;   // softmax-invariant, dropped
    const int*  nodes = (const int*)d_in[7];
    const int*  nidx  = (const int*)d_in[8];
    const void* nmask = d_in[9];

    char* ws = (char*)d_ws;
    int* flags            = (int*)ws;                       // 8 B
    unsigned short* W1top = (unsigned short*)(ws + 1024);   // 8 KB
    unsigned short* W1bot = (unsigned short*)(ws + 1024 + 8192);    // 8 KB
    unsigned short* W2p   = (unsigned short*)(ws + 1024 + 16384);   // 8 KB
    float* UW             = (float*)(ws + 32768);           // 4 MB f32 [NN x 64]

    prep_kernel<<<1, 1024, 0, stream>>>((const unsigned int*)table,
                                        (const unsigned int*)nmask,
                                        W1, W2, flags, W1top, W1bot, W2p);
    uw_kernel<<<NN / 256, 256, 0, stream>>>(table, b1, nodes, flags, W1bot, UW);
    agg_kernel<<<NN / 2, 128, 0, stream>>>(table, b2, W3, nidx, nmask,
                                           flags, W1top, W2p, UW, d_out);
}

// Round 2
// 366.980 us; speedup vs baseline: 1.1179x; 1.0332x over previous
//
#include <hip/hip_runtime.h>
#include <hip/hip_bf16.h>

#define NN 16384   // N_NODES
#define KK 50      // K neighbors
#define DD 64      // EMBED_DIM

typedef __attribute__((ext_vector_type(8))) short bf16x8;   // 8 bf16 (4 VGPRs)
typedef __attribute__((ext_vector_type(4))) float f32x4;    // MFMA C/D

// ---------- bf16 helpers ----------
__device__ __forceinline__ float bf2f(unsigned short u) {
    union { unsigned int i; float f; } v;
    v.i = ((unsigned int)u) << 16;
    return v.f;
}
__device__ __forceinline__ unsigned short f2bf(float f) {
    union { float f; unsigned int i; } v; v.f = f;
    unsigned int lsb = (v.i >> 16) & 1u;
    v.i += 0x7fffu + lsb;                 // RTNE
    return (unsigned short)(v.i >> 16);
}
// pack two f32 -> one u32 of 2x bf16 (RTNE), src0 -> low half
__device__ __forceinline__ unsigned int pk2bf(float lo, float hi) {
    unsigned int w;
    asm("v_cvt_pk_bf16_f32 %0, %1, %2" : "=v"(w) : "v"(lo), "v"(hi));
    return w;
}

template<int BF16>
__device__ __forceinline__ float ldv(const void* p, size_t i) {
    if (BF16) return bf2f(((const unsigned short*)p)[i]);
    else      return ((const float*)p)[i];
}

template<int BF16>
__device__ __forceinline__ f32x4 ld4(const void* p, size_t i) {
    if (BF16) {
        const ushort4 u = *(const ushort4*)((const unsigned short*)p + i);
        return (f32x4){bf2f(u.x), bf2f(u.y), bf2f(u.z), bf2f(u.w)};
    } else {
        return *(const f32x4*)((const float*)p + i);
    }
}

// 8 contiguous elements -> bf16x8 fragment.
// f32 path: two dwordx4 loads + 4 cvt_pk.
template<int BF16>
__device__ __forceinline__ bf16x8 load8(const void* p, size_t off) {
    if (BF16) {
        return *(const bf16x8*)((const unsigned short*)p + off);   // 16B
    } else {
        const float* f = (const float*)p + off;                    // 32B aligned
        const f32x4 a = *(const f32x4*)f;
        const f32x4 b = *(const f32x4*)(f + 4);
        union { bf16x8 v; unsigned int w[4]; } r;
        r.w[0] = pk2bf(a[0], a[1]);
        r.w[1] = pk2bf(a[2], a[3]);
        r.w[2] = pk2bf(b[0], b[1]);
        r.w[3] = pk2bf(b[2], b[3]);
        return r.v;
    }
}

// ---------- probe + weight repack (one block, 1024 threads) ----------
// flags[0]: neigh_mask uint8(1)/int32(0); flags[1]: tensors bf16(1)/f32(0)
// Packed as B-fragments of W (== A-fragments of W^T, bit-identical):
//   frag fl = kt*4 + ct, lane l holds W[k = kt*32 + (l>>4)*8 + j][c = ct*16 + (l&15)]
__global__ void prep_kernel(const unsigned int* __restrict__ tw,
                            const unsigned int* __restrict__ mw,
                            const void* __restrict__ W1_,
                            const void* __restrict__ W2_,
                            int* __restrict__ flags,
                            unsigned short* __restrict__ W1top,
                            unsigned short* __restrict__ W1bot,
                            unsigned short* __restrict__ W2p) {
    __shared__ int sflags[2];
    const int t = threadIdx.x;            // 1024
    if (t < 64) {
        const unsigned int w  = tw[t];
        const unsigned int lo = w & 0xFFFFu;
        const unsigned int ex = (lo >> 7) & 0xFFu;
        const bool bf_like = (ex >= 96u && ex <= 126u);
        const unsigned long long bb = __ballot(bf_like);
        bool found = false;
#pragma unroll
        for (int i = 0; i < 8; ++i) found |= (mw[t + i * 64] > 1u);
        const unsigned long long mb = __ballot(found);
        if (t == 0) {
            sflags[0] = (mb != 0ull) ? 1 : 0;
            sflags[1] = (__popcll(bb) >= 48) ? 1 : 0;
            flags[0] = sflags[0];
            flags[1] = sflags[1];
        }
    }
    __syncthreads();
    const int bf = sflags[1];
    {   // W1 [128x64]: 16 fragments; kt<2 -> top (E half), kt>=2 -> bot (U half)
        const int f = t >> 6, lane = t & 63;
        const int kt = f >> 2, nt = f & 3;
        const int q = lane >> 4, col = lane & 15;
#pragma unroll
        for (int j = 0; j < 8; ++j) {
            const int k = kt * 32 + q * 8 + j;
            const int n = nt * 16 + col;
            const float v = bf ? bf2f(((const unsigned short*)W1_)[k * 64 + n])
                               : ((const float*)W1_)[k * 64 + n];
            unsigned short* dst = (kt < 2) ? W1top : W1bot;
            const int fl = ((kt & 1) * 4 + nt);
            dst[((size_t)fl * 64 + lane) * 8 + j] = f2bf(v);
        }
    }
    if (t < 512) {   // W2 [64x64]: 8 fragments
        const int f = t >> 6, lane = t & 63;
        const int kt = f >> 2, nt = f & 3;
        const int q = lane >> 4, col = lane & 15;
#pragma unroll
        for (int j = 0; j < 8; ++j) {
            const int k = kt * 32 + q * 8 + j;
            const int n = nt * 16 + col;
            const float v = bf ? bf2f(((const unsigned short*)W2_)[k * 64 + n])
                               : ((const float*)W2_)[k * 64 + n];
            W2p[((size_t)f * 64 + lane) * 8 + j] = f2bf(v);
        }
    }
}

// ---------- main: one wave per node, 4 waves/block ----------
// TRANSPOSED scheme: A-frag(M) == B-frag(M^T) bit-for-bit, so
//   mfma(Wfrag, Efrag) computes H^T[c][m] directly. Lane owns
//   h[m = mt*16+col][c = ct*16+q*4+r]; scores/softmax/att are lane-local
//   over the same m the E-fragments live on.
// The center-node term UW[n][c] = b1[c] + U @ W1bot is fused in-wave:
//   mfma(W1bot_frag, broadcast-U-frag) yields UW in exactly the uw4 lane
//   layout (c = ct*16+q*4+r, replicated over col). No uw kernel, no UW buffer.
template<int BF16>
__device__ __forceinline__ void agg_impl(
    const void* __restrict__ table_,
    const void* __restrict__ b1_,
    const void* __restrict__ b2_, const void* __restrict__ W3_,
    const int*  __restrict__ nodes,
    const int*  __restrict__ neigh_idx,
    const void* __restrict__ neigh_mask,
    int mu8,
    const unsigned short* __restrict__ W1top,
    const unsigned short* __restrict__ W1bot,
    const unsigned short* __restrict__ W2p,
    unsigned short* __restrict__ h1,     // per-wave [64][72] bf16 (h[m][c]); reused as f32 scratch
    void* __restrict__ out_)
{
    const int lane = threadIdx.x & 63;
    const int n    = blockIdx.x * 4 + (threadIdx.x >> 6);
    const int q    = lane >> 4;
    const int col  = lane & 15;

    // --- indices + mask: issue both loads in parallel (no mask->idx chain);
    //     masked/padded rows redirected to row 0 (keeps gather traffic halved) ---
    int  rowidx [4];
    bool rowmask[4];
#pragma unroll
    for (int mt = 0; mt < 4; ++mt) {
        const int k  = mt * 16 + col;
        const int kc = (k < KK) ? k : (KK - 1);
        const int ir = neigh_idx[(size_t)n * KK + kc];
        bool mk = mu8 ? (((const unsigned char*)neigh_mask)[(size_t)n * KK + kc] != 0)
                      : (((const int*)neigh_mask)[(size_t)n * KK + kc] != 0);
        mk = mk && (k < KK);
        rowmask[mt] = mk;
        rowidx[mt]  = mk ? ir : 0;
    }

    // --- center row U (wave-uniform node; broadcast loads) ---
    const size_t urow = (size_t)nodes[n];
    bf16x8 ufrag[2];
#pragma unroll
    for (int kt = 0; kt < 2; ++kt)
        ufrag[kt] = load8<BF16>(table_, urow * 64 + kt * 32 + q * 8);

    // --- gather E rows (kept live for the final weighted sum) ---
    bf16x8 afrag[4][2];
#pragma unroll
    for (int mt = 0; mt < 4; ++mt)
#pragma unroll
        for (int kt = 0; kt < 2; ++kt)
            afrag[mt][kt] = load8<BF16>(table_, (size_t)rowidx[mt] * 64 + kt * 32 + q * 8);

    // --- layer 1 transposed, streamed over c-tiles, center term fused ---
#pragma unroll
    for (int ct = 0; ct < 4; ++ct) {
        const bf16x8 wA0 = *(const bf16x8*)(W1top + ((size_t)(0 * 4 + ct) * 64 + lane) * 8);
        const bf16x8 wA1 = *(const bf16x8*)(W1top + ((size_t)(1 * 4 + ct) * 64 + lane) * 8);
        const bf16x8 uB0 = *(const bf16x8*)(W1bot + ((size_t)(0 * 4 + ct) * 64 + lane) * 8);
        const bf16x8 uB1 = *(const bf16x8*)(W1bot + ((size_t)(1 * 4 + ct) * 64 + lane) * 8);
        f32x4 acc[4];
#pragma unroll
        for (int mt = 0; mt < 4; ++mt) acc[mt] = (f32x4){0.f, 0.f, 0.f, 0.f};
        f32x4 accu = (f32x4){0.f, 0.f, 0.f, 0.f};
#pragma unroll
        for (int mt = 0; mt < 4; ++mt)
            acc[mt] = __builtin_amdgcn_mfma_f32_16x16x32_bf16(wA0, afrag[mt][0], acc[mt], 0, 0, 0);
        accu = __builtin_amdgcn_mfma_f32_16x16x32_bf16(uB0, ufrag[0], accu, 0, 0, 0);
#pragma unroll
        for (int mt = 0; mt < 4; ++mt)
            acc[mt] = __builtin_amdgcn_mfma_f32_16x16x32_bf16(wA1, afrag[mt][1], acc[mt], 0, 0, 0);
        accu = __builtin_amdgcn_mfma_f32_16x16x32_bf16(uB1, ufrag[1], accu, 0, 0, 0);

        const f32x4 b1v = ld4<BF16>(b1_, ct * 16 + q * 4);
        const float uw0 = accu[0] + b1v[0];
        const float uw1 = accu[1] + b1v[1];
        const float uw2 = accu[2] + b1v[2];
        const float uw3 = accu[3] + b1v[3];
#pragma unroll
        for (int mt = 0; mt < 4; ++mt) {
            const float h0 = fmaxf(acc[mt][0] + uw0, 0.f);
            const float hv1 = fmaxf(acc[mt][1] + uw1, 0.f);
            const float h2 = fmaxf(acc[mt][2] + uw2, 0.f);
            const float h3 = fmaxf(acc[mt][3] + uw3, 0.f);
            uint2 w;                       // 4 consecutive c -> one b64 store
            w.x = pk2bf(h0, hv1);
            w.y = pk2bf(h2, h3);
            *(uint2*)&h1[(size_t)(mt * 16 + col) * 72 + ct * 16 + q * 4] = w;
        }
    }
    __builtin_amdgcn_wave_barrier();

    // --- B2 fragments: lane reads h[m=mt*16+col][c = kt*32+q*8+j] (b128) ---
    bf16x8 bfrag[4][2];
#pragma unroll
    for (int mt = 0; mt < 4; ++mt)
#pragma unroll
        for (int kt = 0; kt < 2; ++kt)
            bfrag[mt][kt] = *(const bf16x8*)&h1[(size_t)(mt * 16 + col) * 72 + kt * 32 + q * 8];

    // --- layer 2 transposed, streamed over c'-tiles; fold b2/W3 immediately ---
    float p[4] = {0.f, 0.f, 0.f, 0.f};
#pragma unroll
    for (int ct = 0; ct < 4; ++ct) {
        const bf16x8 wB0 = *(const bf16x8*)(W2p + ((size_t)(0 * 4 + ct) * 64 + lane) * 8);
        const bf16x8 wB1 = *(const bf16x8*)(W2p + ((size_t)(1 * 4 + ct) * 64 + lane) * 8);
        f32x4 acc[4];
#pragma unroll
        for (int mt = 0; mt < 4; ++mt) acc[mt] = (f32x4){0.f, 0.f, 0.f, 0.f};
#pragma unroll
        for (int mt = 0; mt < 4; ++mt)
            acc[mt] = __builtin_amdgcn_mfma_f32_16x16x32_bf16(wB0, bfrag[mt][0], acc[mt], 0, 0, 0);
#pragma unroll
        for (int mt = 0; mt < 4; ++mt)
            acc[mt] = __builtin_amdgcn_mfma_f32_16x16x32_bf16(wB1, bfrag[mt][1], acc[mt], 0, 0, 0);

        const f32x4 b2v = ld4<BF16>(b2_, ct * 16 + q * 4);
        const f32x4 w3v = ld4<BF16>(W3_, ct * 16 + q * 4);
#pragma unroll
        for (int mt = 0; mt < 4; ++mt) {
            float t = 0.f;
#pragma unroll
            for (int r = 0; r < 4; ++r)
                t += fmaxf(acc[mt][r] + b2v[r], 0.f) * w3v[r];
            p[mt] += t;
        }
    }

    // --- finish scores: sum the 4 q-lanes, apply mask ---
#pragma unroll
    for (int mt = 0; mt < 4; ++mt) {
        p[mt] += __shfl_xor(p[mt], 16, 64);
        p[mt] += __shfl_xor(p[mt], 32, 64);
        if (!rowmask[mt]) p[mt] = -1.0e30f;
    }

    // --- masked softmax over 64 m (4 per lane x 16 cols, replicated over q) ---
    float mx = fmaxf(fmaxf(p[0], p[1]), fmaxf(p[2], p[3]));
    mx = fmaxf(mx, __shfl_xor(mx, 1, 64));
    mx = fmaxf(mx, __shfl_xor(mx, 2, 64));
    mx = fmaxf(mx, __shfl_xor(mx, 4, 64));
    mx = fmaxf(mx, __shfl_xor(mx, 8, 64));

    float e[4], ls = 0.f;
#pragma unroll
    for (int mt = 0; mt < 4; ++mt) { e[mt] = __expf(p[mt] - mx); ls += e[mt]; }
    ls += __shfl_xor(ls, 1, 64);
    ls += __shfl_xor(ls, 2, 64);
    ls += __shfl_xor(ls, 4, 64);
    ls += __shfl_xor(ls, 8, 64);
    const float inv = 1.f / ls;

    // att[m=mt*16+col] lands exactly on the lanes holding E[m] — no broadcast.
    float att[4];
#pragma unroll
    for (int mt = 0; mt < 4; ++mt) att[mt] = e[mt] * inv;

    // --- out[d] = sum_m att[m]*E[m][d]: per-lane partials over its 4 m's ---
    float v[2][8];
#pragma unroll
    for (int kt = 0; kt < 2; ++kt)
#pragma unroll
        for (int j = 0; j < 8; ++j) v[kt][j] = 0.f;
#pragma unroll
    for (int mt = 0; mt < 4; ++mt)
#pragma unroll
        for (int kt = 0; kt < 2; ++kt)
#pragma unroll
            for (int j = 0; j < 8; ++j)
                v[kt][j] += att[mt] * bf2f(((const unsigned short*)&afrag[mt][kt])[j]);

    // --- col-reduce via LDS scatter/gather (reuse h1 as f32 scratch, stride 20):
    //     lane writes part[d][col] for its 16 d's; lane `lane` then owns out[lane].
    //     16 ds_write_b32 + 4 ds_read_b128 + 15 adds vs 64 swizzles + broadcast. ---
    float* part = (float*)h1;            // 64 rows x 20 f32 = 5120 B <= 9216 B
    __builtin_amdgcn_wave_barrier();
#pragma unroll
    for (int kt = 0; kt < 2; ++kt)
#pragma unroll
        for (int j = 0; j < 8; ++j)
            part[(kt * 32 + q * 8 + j) * 20 + col] = v[kt][j];
    __builtin_amdgcn_wave_barrier();

    const f32x4 s0 = *(const f32x4*)&part[lane * 20 + 0];
    const f32x4 s1 = *(const f32x4*)&part[lane * 20 + 4];
    const f32x4 s2 = *(const f32x4*)&part[lane * 20 + 8];
    const f32x4 s3 = *(const f32x4*)&part[lane * 20 + 12];
    const float res = (((s0[0] + s0[1]) + (s0[2] + s0[3]))
                     + ((s1[0] + s1[1]) + (s1[2] + s1[3])))
                    + (((s2[0] + s2[1]) + (s2[2] + s2[3]))
                     + ((s3[0] + s3[1]) + (s3[2] + s3[3])));

    if (BF16) ((unsigned short*)out_)[(size_t)n * 64 + lane] = f2bf(res);
    else      ((float*)out_)[(size_t)n * 64 + lane] = res;
}

__global__ __launch_bounds__(256, 4) void agg_kernel(
    const void* __restrict__ table_,
    const void* __restrict__ b1_,
    const void* __restrict__ b2_, const void* __restrict__ W3_,
    const int*  __restrict__ nodes,
    const int*  __restrict__ neigh_idx,
    const void* __restrict__ neigh_mask,
    const int*  __restrict__ flags,
    const unsigned short* __restrict__ W1top,
    const unsigned short* __restrict__ W1bot,
    const unsigned short* __restrict__ W2p,
    void* __restrict__ out_)
{
    __shared__ unsigned short h1_sh[4][64][72];   // 36,864 B/block
    const int wave = threadIdx.x >> 6;
    if (flags[1])
        agg_impl<1>(table_, b1_, b2_, W3_, nodes, neigh_idx, neigh_mask, flags[0],
                    W1top, W1bot, W2p, &h1_sh[wave][0][0], out_);
    else
        agg_impl<0>(table_, b1_, b2_, W3_, nodes, neigh_idx, neigh_mask, flags[0],
                    W1top, W1bot, W2p, &h1_sh[wave][0][0], out_);
}

extern "C" void kernel_launch(void* const* d_in, const int* in_sizes, int n_in,
                              void* d_out, int out_size, void* d_ws, size_t ws_size,
                              hipStream_t stream) {
    const void* table = d_in[0];
    const void* W1    = d_in[1];
    const void* b1    = d_in[2];
    const void* W2    = d_in[3];
    const void* b2    = d_in[4];
    const void* W3    = d_in[5];
    const void* b3    = d_in[6]; (void)b3;   // softmax-invariant, dropped
    const int*  nodes = (const int*)d_in[7];
    const int*  nidx  = (const int*)d_in[8];
    const void* nmask = d_in[9];

    char* ws = (char*)d_ws;
    int* flags            = (int*)ws;                       // 8 B
    unsigned short* W1top = (unsigned short*)(ws + 1024);   // 8 KB
    unsigned short* W1bot = (unsigned short*)(ws + 1024 + 8192);    // 8 KB
    unsigned short* W2p   = (unsigned short*)(ws + 1024 + 16384);   // 8 KB

    prep_kernel<<<1, 1024, 0, stream>>>((const unsigned int*)table,
                                        (const unsigned int*)nmask,
                                        W1, W2, flags, W1top, W1bot, W2p);
    agg_kernel<<<NN / 4, 256, 0, stream>>>(table, b1, b2, W3, nodes, nidx, nmask,
                                           flags, W1top, W1bot, W2p, d_out);
}